// Round 1
// baseline (2005.231 us; speedup 1.0000x reference)
//
#include <hip/hip_runtime.h>

#define PI_F 3.14159265358979323846f

#define NCH   1000
#define NPTS  30000
#define NHALF 15000      // NPTS/2 packed complex samples
#define NFFT  32768      // complex FFT length (real length 65536)
#define NBF   4096       // butterflies per channel per pass (NFFT/8)
#define STR   32770      // per-channel stride in complex elements (room for bin 32768)
#define XCOR  59999

__device__ __forceinline__ float2 cadd(float2 a, float2 b){ return make_float2(a.x+b.x, a.y+b.y); }
__device__ __forceinline__ float2 csub(float2 a, float2 b){ return make_float2(a.x-b.x, a.y-b.y); }
__device__ __forceinline__ float2 cmul(float2 a, float2 b){ return make_float2(a.x*b.x - a.y*b.y, a.x*b.y + a.y*b.x); }

// S*i*z  (S = -1 forward, +1 inverse)
template<int S>
__device__ __forceinline__ float2 mulIs(float2 z){ return make_float2(-(float)S*z.y, (float)S*z.x); }

// 8-point DFT, ω = e^{S*2πi/8}
template<int S>
__device__ __forceinline__ void dft8(float2 v[8]){
  const float r2 = 0.7071067811865476f;
  const float sf = (float)S;
  float2 ea=cadd(v[0],v[4]), eb=csub(v[0],v[4]);
  float2 ec=cadd(v[2],v[6]), ed=csub(v[2],v[6]);
  float2 oa=cadd(v[1],v[5]), ob=csub(v[1],v[5]);
  float2 oc=cadd(v[3],v[7]), od=csub(v[3],v[7]);
  float2 ied=mulIs<S>(ed), iod=mulIs<S>(od);
  float2 E0=cadd(ea,ec), E2=csub(ea,ec), E1=cadd(eb,ied), E3=csub(eb,ied);
  float2 O0=cadd(oa,oc), O2=csub(oa,oc), O1=cadd(ob,iod), O3=csub(ob,iod);
  float2 T1 = make_float2(r2*(O1.x - sf*O1.y), r2*(O1.y + sf*O1.x));   // ω^1·O1
  float2 T2 = mulIs<S>(O2);                                            // ω^2·O2
  float2 T3 = make_float2(r2*(-O3.x - sf*O3.y), r2*(sf*O3.x - O3.y));  // ω^3·O3
  v[0]=cadd(E0,O0); v[4]=csub(E0,O0);
  v[1]=cadd(E1,T1); v[5]=csub(E1,T1);
  v[2]=cadd(E2,T2); v[6]=csub(E2,T2);
  v[3]=cadd(E3,T3); v[7]=csub(E3,T3);
}

// ---------- forward pass 1 (Ns=1), fused with real-pair packing + zero pad ----------
__global__ __launch_bounds__(256) void fft_fwd_p1(const float* __restrict__ d1, const float* __restrict__ d2,
                                                  float2* __restrict__ out, int cb, int ch0)
{
  int tid = blockIdx.x*256 + threadIdx.x;
  int c = tid >> 12;
  int j = tid & (NBF-1);
  const float* src = (c < cb) ? (d1 + (size_t)(ch0 + c) * NPTS)
                              : (d2 + (size_t)(ch0 + c - cb) * NPTS);
  const float2* src2 = reinterpret_cast<const float2*>(src);
  float2 v[8];
  #pragma unroll
  for (int r = 0; r < 8; ++r) {
    int m = j + (r << 12);
    v[r] = (m < NHALF) ? src2[m] : make_float2(0.f, 0.f);
  }
  dft8<-1>(v);
  float2* dst = out + (size_t)c * STR + (size_t)j * 8;
  #pragma unroll
  for (int r = 0; r < 8; ++r) dst[r] = v[r];
}

// ---------- generic Stockham radix-8 pass, Ns = 2^LG ----------
template<int LG, int S>
__global__ __launch_bounds__(256) void fft_pass(const float2* __restrict__ in, float2* __restrict__ out)
{
  int tid = blockIdx.x*256 + threadIdx.x;
  int c = tid >> 12;
  int j = tid & (NBF-1);
  const float2* src = in + (size_t)c * STR;
  float2 v[8];
  #pragma unroll
  for (int r = 0; r < 8; ++r) v[r] = src[j + (r << 12)];
  constexpr int NS = 1 << LG;
  int jm = j & (NS - 1);
  if constexpr (LG > 0) {
    float ang = (float)S * (2.0f*PI_F) * (float)jm / (float)(NS*8);
    float sn, cs; __sincosf(ang, &sn, &cs);
    float2 w1 = make_float2(cs, sn);
    float2 wr = w1;
    v[1] = cmul(v[1], wr);
    #pragma unroll
    for (int r = 2; r < 8; ++r) { wr = cmul(wr, w1); v[r] = cmul(v[r], wr); }
  }
  dft8<S>(v);
  int idxD = ((j >> LG) << (LG+3)) + jm;
  float2* dst = out + (size_t)c * STR + idxD;
  #pragma unroll
  for (int r = 0; r < 8; ++r) dst[(size_t)(r << LG)] = v[r];
}

// ---------- whitening: rfft unpack + running-abs-mean + tapers, in place ----------
__device__ __forceinline__ int padidx(int m){ return m + (m >> 5); }

__global__ __launch_bounds__(1024) void whiten_kernel(float2* __restrict__ buf)
{
  const int ch = blockIdx.x;
  const int t  = threadIdx.x;
  float2* Z = buf + (size_t)ch * STR;
  __shared__ float s[33793];     // 32769 magnitudes, padded every 32
  __shared__ float wsums[16];

  float2 X[33];
  // phase 1: unpack X[k] from Z[k], Z[N-k]; magnitudes to LDS
  #pragma unroll
  for (int i = 0; i < 33; ++i) {
    int k = i*1024 + t;
    if (i < 32 || t == 0) {
      float2 zk = Z[k & (NFFT-1)];
      float2 zn = Z[(NFFT - k) & (NFFT-1)];
      float2 xe = make_float2(0.5f*(zk.x+zn.x), 0.5f*(zk.y-zn.y));
      float2 xh = make_float2(0.5f*(zk.x-zn.x), 0.5f*(zk.y+zn.y)); // (zk-conj(zn))/2
      float2 xo = make_float2(xh.y, -xh.x);                        // /i
      float ang = -PI_F * (float)k * (1.0f/32768.0f);
      float sn, cs; __sincosf(ang, &sn, &cs);
      float2 w = make_float2(cs, sn);
      X[i] = cadd(xe, cmul(w, xo));
      s[padidx(k)] = sqrtf(X[i].x*X[i].x + X[i].y*X[i].y);
    }
  }
  __syncthreads();

  // phase 2: block-wide inclusive cumsum of magnitudes (in place in LDS)
  const int base = t*32;
  float sum = 0.f;
  #pragma unroll
  for (int q = 0; q < 32; ++q) sum += s[padidx(base+q)];
  if (t == 1023) sum += s[padidx(32768)];
  const int lane = t & 63, wid = t >> 6;
  float v = sum;
  #pragma unroll
  for (int off = 1; off < 64; off <<= 1) {
    float u = __shfl_up(v, off);
    if (lane >= off) v += u;
  }
  if (lane == 63) wsums[wid] = v;
  __syncthreads();
  float wexcl = 0.f;
  for (int w = 0; w < 16; ++w) wexcl += (w < wid) ? wsums[w] : 0.f;
  float run = wexcl + (v - sum);       // exclusive prefix of this thread's chunk
  #pragma unroll
  for (int q = 0; q < 32; ++q) {
    int idx = padidx(base+q);
    run += s[idx];
    s[idx] = run;
  }
  if (t == 1023) { int idx = padidx(32768); run += s[idx]; s[idx] = run; }
  __syncthreads();

  // phase 3: smoothed = edge-clamped 655-bin box mean; whiten + taper; write W in place
  const float a0 = s[padidx(0)];
  const float alast = s[padidx(32768)] - s[padidx(32767)];
  #pragma unroll
  for (int i = 0; i < 33; ++i) {
    int k = i*1024 + t;
    if (i < 32 || t == 0) {
      int hi = k + 327; if (hi > 32768) hi = 32768;
      int lom1 = k - 328;
      float Shi = s[padidx(hi)];
      float Slo = (lom1 >= 0) ? s[padidx(lom1)] : 0.f;
      float lc = (k < 327) ? (float)(327 - k) : 0.f;
      float rc = (k > 32441) ? (float)(k - 32441) : 0.f;
      float smoothed = (lc*a0 + (Shi - Slo) + rc*alast) * (1.0f/655.0f);
      float2 wv;
      if (smoothed > 0.f) {
        float inv = 1.0f / smoothed;
        wv = make_float2(X[i].x*inv, X[i].y*inv);
      } else wv = make_float2(0.f, 0.f);
      float tp = 1.0f;
      if (k < 131)        { float th = (float)k * (PI_F/260.0f);           float sn = __sinf(th); tp = sn*sn; }
      else if (k >= 13108){ float th = (float)(k-13108) * (PI_F/39320.0f); float cs = __cosf(th); tp = cs*cs; }
      wv.x *= tp; wv.y *= tp;
      Z[k] = wv;
    }
  }
}

// ---------- cross-spectrum + irfft packing: Zinv = (Xe + i*Xo)/N ----------
__global__ __launch_bounds__(256) void cross_pack(const float2* __restrict__ W, float2* __restrict__ Zo, int cb)
{
  int tid = blockIdx.x*256 + threadIdx.x;
  int c = tid / 16640;
  int k = tid - c*16640;
  if (k > 16384 || c >= cb) return;
  const float2* W1 = W + (size_t)c * STR;
  const float2* W2 = W + (size_t)(cb + c) * STR;
  float2 a1 = W1[k],        b1 = W2[k];
  float2 a2 = W1[NFFT - k], b2 = W2[NFFT - k];
  // C = conj(W1)*W2
  float2 Ck = make_float2(a1.x*b1.x + a1.y*b1.y, a1.x*b1.y - a1.y*b1.x);
  float2 Cn = make_float2(a2.x*b2.x + a2.y*b2.y, a2.x*b2.y - a2.y*b2.x);
  float ang = PI_F * (float)k * (1.0f/32768.0f);
  float sn, cs; __sincosf(ang, &sn, &cs);
  const float scale = 1.0f/32768.0f;
  float2* dst = Zo + (size_t)c * STR;
  // Zinv[k]: Xe=(Ck+conj(Cn))/2, Xo=e^{+iπk/N}(Ck-conj(Cn))/2
  {
    float2 xe = make_float2(0.5f*(Ck.x+Cn.x), 0.5f*(Ck.y-Cn.y));
    float2 d  = make_float2(0.5f*(Ck.x-Cn.x), 0.5f*(Ck.y+Cn.y));
    float2 w  = make_float2(cs, sn);
    float2 xo = cmul(w, d);
    dst[k] = make_float2((xe.x - xo.y)*scale, (xe.y + xo.x)*scale);
  }
  if (k > 0 && k < 16384) {
    // Zinv[N-k]: e^{iπ(N-k)/N} = (-cs, sn)
    float2 xe = make_float2(0.5f*(Cn.x+Ck.x), 0.5f*(Cn.y-Ck.y));
    float2 d  = make_float2(0.5f*(Cn.x-Ck.x), 0.5f*(Cn.y+Ck.y));
    float2 w  = make_float2(-cs, sn);
    float2 xo = cmul(w, d);
    dst[NFFT - k] = make_float2((xe.x - xo.y)*scale, (xe.y + xo.x)*scale);
  }
}

// ---------- inverse final pass (Ns=4096), fused unpack + roll + slice ----------
__global__ __launch_bounds__(256) void fft_inv_final(const float2* __restrict__ in, float* __restrict__ out, int ch0)
{
  int tid = blockIdx.x*256 + threadIdx.x;
  int c = tid >> 12;
  int j = tid & (NBF-1);
  const float2* src = in + (size_t)c * STR;
  float2 v[8];
  #pragma unroll
  for (int r = 0; r < 8; ++r) v[r] = src[j + (r << 12)];
  float ang = (2.0f*PI_F) * (float)j * (1.0f/32768.0f);
  float sn, cs; __sincosf(ang, &sn, &cs);
  float2 w1 = make_float2(cs, sn);
  float2 wr = w1;
  v[1] = cmul(v[1], wr);
  #pragma unroll
  for (int r = 2; r < 8; ++r) { wr = cmul(wr, w1); v[r] = cmul(v[r], wr); }
  dft8<1>(v);
  float* o = out + (size_t)(ch0 + c) * XCOR;
  // cc[m]: m=2n -> Re, m=2n+1 -> Im ; out[j]=cc[(j-29999) mod 65536]
  #pragma unroll
  for (int r = 0; r < 8; ++r) {
    int n = j + (r << 12);
    int m = 2*n;
    int j1 = (m <= 29999) ? (m + 29999) : ((m >= 35537) ? (m - 35537) : -1);
    if (j1 >= 0) o[j1] = v[r].x;
    int m2 = m + 1;
    int j2 = (m2 <= 29999) ? (m2 + 29999) : ((m2 >= 35537) ? (m2 - 35537) : -1);
    if (j2 >= 0) o[j2] = v[r].y;
  }
}

__global__ void diag_kernel(float* out, float vv){ if (threadIdx.x==0 && blockIdx.x==0) out[0] = vv; }

extern "C" void kernel_launch(void* const* d_in, const int* in_sizes, int n_in,
                              void* d_out, int out_size, void* d_ws, size_t ws_size,
                              hipStream_t stream)
{
  const float* d1 = (const float*)d_in[0];
  const float* d2 = (const float*)d_in[1];
  float* out = (float*)d_out;

  // bytes per channel-pair of batch: 2 buffers * 2 arrays * STR complex
  const size_t bytesPerCh = 2ULL * 2ULL * (size_t)STR * sizeof(float2); // 1,048,640
  int CB = (int)(ws_size / bytesPerCh);
  if (CB > NCH) CB = NCH;
  if (CB < 1) { diag_kernel<<<1,1,0,stream>>>(out, (float)ws_size); return; }

  float2* bufA = (float2*)d_ws;
  float2* bufB = bufA + (size_t)2 * CB * STR;

  for (int ch0 = 0; ch0 < NCH; ch0 += CB) {
    int cb = (NCH - ch0 < CB) ? (NCH - ch0) : CB;
    int nch2 = 2*cb;
    dim3 thr(256);
    dim3 blkF(nch2*16), blkI(cb*16);

    // forward FFT (both arrays batched), 5 radix-8 Stockham passes
    fft_fwd_p1      <<<blkF, thr, 0, stream>>>(d1, d2, bufA, cb, ch0);
    fft_pass<3,-1>  <<<blkF, thr, 0, stream>>>(bufA, bufB);
    fft_pass<6,-1>  <<<blkF, thr, 0, stream>>>(bufB, bufA);
    fft_pass<9,-1>  <<<blkF, thr, 0, stream>>>(bufA, bufB);
    fft_pass<12,-1> <<<blkF, thr, 0, stream>>>(bufB, bufA);

    // spectral whitening in place (unpack -> running abs mean -> taper)
    whiten_kernel   <<<dim3(nch2), dim3(1024), 0, stream>>>(bufA);

    // conj(W1)*W2 + irfft pack (scale 1/N folded in)
    cross_pack      <<<dim3(cb*65), thr, 0, stream>>>(bufA, bufB, cb);

    // inverse FFT, 5 passes; final fused with roll + central slice
    fft_pass<0,1>   <<<blkI, thr, 0, stream>>>(bufB, bufA);
    fft_pass<3,1>   <<<blkI, thr, 0, stream>>>(bufA, bufB);
    fft_pass<6,1>   <<<blkI, thr, 0, stream>>>(bufB, bufA);
    fft_pass<9,1>   <<<blkI, thr, 0, stream>>>(bufA, bufB);
    fft_inv_final   <<<blkI, thr, 0, stream>>>(bufB, out, ch0);
  }
}

// Round 2
// 1527.044 us; speedup vs baseline: 1.3131x; 1.3131x over previous
//
#include <hip/hip_runtime.h>

#define PI_F 3.14159265358979323846f

#define NCH   1000
#define NPTS  30000
#define NHALF 15000      // NPTS/2 packed complex samples
#define NFFT  32768      // complex FFT length (real length 65536)
#define NBF32 1024       // butterflies per channel per radix-32 pass (NFFT/32)
#define STR   32770      // per-channel stride in complex elements (room for bin 32768)
#define XCOR  59999

__device__ __forceinline__ float2 cadd(float2 a, float2 b){ return make_float2(a.x+b.x, a.y+b.y); }
__device__ __forceinline__ float2 csub(float2 a, float2 b){ return make_float2(a.x-b.x, a.y-b.y); }
__device__ __forceinline__ float2 cmul(float2 a, float2 b){ return make_float2(a.x*b.x - a.y*b.y, a.x*b.y + a.y*b.x); }

// S*i*z  (S = -1 forward, +1 inverse)
template<int S>
__device__ __forceinline__ float2 mulIs(float2 z){ return make_float2(-(float)S*z.y, (float)S*z.x); }

// 8-point DFT, ω = e^{S*2πi/8}
template<int S>
__device__ __forceinline__ void dft8(float2 v[8]){
  const float r2 = 0.7071067811865476f;
  const float sf = (float)S;
  float2 ea=cadd(v[0],v[4]), eb=csub(v[0],v[4]);
  float2 ec=cadd(v[2],v[6]), ed=csub(v[2],v[6]);
  float2 oa=cadd(v[1],v[5]), ob=csub(v[1],v[5]);
  float2 oc=cadd(v[3],v[7]), od=csub(v[3],v[7]);
  float2 ied=mulIs<S>(ed), iod=mulIs<S>(od);
  float2 E0=cadd(ea,ec), E2=csub(ea,ec), E1=cadd(eb,ied), E3=csub(eb,ied);
  float2 O0=cadd(oa,oc), O2=csub(oa,oc), O1=cadd(ob,iod), O3=csub(ob,iod);
  float2 T1 = make_float2(r2*(O1.x - sf*O1.y), r2*(O1.y + sf*O1.x));   // ω^1·O1
  float2 T2 = mulIs<S>(O2);                                            // ω^2·O2
  float2 T3 = make_float2(r2*(-O3.x - sf*O3.y), r2*(sf*O3.x - O3.y));  // ω^3·O3
  v[0]=cadd(E0,O0); v[4]=csub(E0,O0);
  v[1]=cadd(E1,T1); v[5]=csub(E1,T1);
  v[2]=cadd(E2,T2); v[6]=csub(E2,T2);
  v[3]=cadd(E3,T3); v[7]=csub(E3,T3);
}

// 4-point DFT, ω = e^{S*2πi/4} = S*i
template<int S>
__device__ __forceinline__ void dft4(float2 v[4]){
  float2 t0=cadd(v[0],v[2]), t1=csub(v[0],v[2]);
  float2 t2=cadd(v[1],v[3]), t3=mulIs<S>(csub(v[1],v[3]));
  v[0]=cadd(t0,t2); v[2]=csub(t0,t2);
  v[1]=cadd(t1,t3); v[3]=csub(t1,t3);
}

// 32-point DFT in registers: n = 4a+b -> 4×DFT8 (over a), constant twiddles W32^{b·k1}, 8×DFT4 (over b)
// X[k1 + 8*k2] = DFT4_b( W32^{b·k1} · DFT8_a(x[4a+b])[k1] )[k2]
template<int S>
__device__ __forceinline__ void dft32(float2 v[32]){
  constexpr float TC[22] = {
    1.f, 0.98078528040323044f, 0.92387953251128674f, 0.83146961230254524f,
    0.70710678118654757f, 0.55557023301960218f, 0.38268343236508978f, 0.19509032201612825f,
    0.f, -0.19509032201612825f, -0.38268343236508978f, -0.55557023301960218f,
    -0.70710678118654757f, -0.83146961230254524f, -0.92387953251128674f, -0.98078528040323044f,
    -1.f, -0.98078528040323044f, -0.92387953251128674f, -0.83146961230254524f,
    -0.70710678118654757f, -0.55557023301960218f };
  constexpr float TS[22] = {
    0.f, 0.19509032201612825f, 0.38268343236508978f, 0.55557023301960218f,
    0.70710678118654757f, 0.83146961230254524f, 0.92387953251128674f, 0.98078528040323044f,
    1.f, 0.98078528040323044f, 0.92387953251128674f, 0.83146961230254524f,
    0.70710678118654757f, 0.55557023301960218f, 0.38268343236508978f, 0.19509032201612825f,
    0.f, -0.19509032201612825f, -0.38268343236508978f, -0.55557023301960218f,
    -0.70710678118654757f, -0.83146961230254524f };
  float2 y[4][8];
  #pragma unroll
  for (int b = 0; b < 4; ++b)
    #pragma unroll
    for (int a = 0; a < 8; ++a) y[b][a] = v[4*a + b];
  #pragma unroll
  for (int b = 0; b < 4; ++b) dft8<S>(y[b]);
  #pragma unroll
  for (int b = 1; b < 4; ++b)
    #pragma unroll
    for (int k1 = 1; k1 < 8; ++k1) {
      int m = b*k1;
      float2 w = make_float2(TC[m], (float)S * TS[m]);
      y[b][k1] = cmul(y[b][k1], w);
    }
  #pragma unroll
  for (int k1 = 0; k1 < 8; ++k1) {
    float2 z[4] = { y[0][k1], y[1][k1], y[2][k1], y[3][k1] };
    dft4<S>(z);
    #pragma unroll
    for (int k2 = 0; k2 < 4; ++k2) v[k1 + 8*k2] = z[k2];
  }
}

// Stockham-stage twiddles: v[r] *= w^r, w = e^{S*2πi*jm/(NS*32)}; depth-≤8 chains off 2 sincos
template<int S>
__device__ __forceinline__ void stage_twiddle32(float2 v[32], float ang){
  float s1,c1,s8,c8;
  __sincosf(ang, &s1, &c1);
  __sincosf(8.f*ang, &s8, &c8);
  float2 w1 = make_float2(c1, s1), w8 = make_float2(c8, s8);
  float2 w16 = cmul(w8, w8), w24 = cmul(w16, w8);
  float2 base[4] = { make_float2(1.f, 0.f), w8, w16, w24 };
  #pragma unroll
  for (int m = 0; m < 4; ++m) {
    float2 wr = base[m];
    if (m > 0) v[8*m] = cmul(v[8*m], wr);
    #pragma unroll
    for (int l = 1; l < 8; ++l) { wr = cmul(wr, w1); v[8*m+l] = cmul(v[8*m+l], wr); }
  }
}

// ---------- forward pass 1 (Ns=1, radix-32), fused with real-pair packing + zero pad ----------
__global__ __launch_bounds__(256) void fft_fwd_p1_r32(const float* __restrict__ d1, const float* __restrict__ d2,
                                                      float2* __restrict__ out, int cb, int ch0)
{
  int tid = blockIdx.x*256 + threadIdx.x;
  int c = tid >> 10;
  int j = tid & (NBF32-1);
  const float* src = (c < cb) ? (d1 + (size_t)(ch0 + c) * NPTS)
                              : (d2 + (size_t)(ch0 + c - cb) * NPTS);
  const float2* src2 = reinterpret_cast<const float2*>(src);
  float2 v[32];
  #pragma unroll
  for (int r = 0; r < 32; ++r) {
    int m = j + (r << 10);
    v[r] = (m < NHALF) ? src2[m] : make_float2(0.f, 0.f);
  }
  dft32<-1>(v);
  float2* dst = out + (size_t)c * STR + (size_t)j * 32;
  #pragma unroll
  for (int r = 0; r < 32; r += 2)
    *reinterpret_cast<float4*>(dst + r) = make_float4(v[r].x, v[r].y, v[r+1].x, v[r+1].y);
}

// ---------- generic Stockham radix-32 pass, Ns = 2^LG ----------
template<int LG, int S>
__global__ __launch_bounds__(256) void fft_pass32(const float2* __restrict__ in, float2* __restrict__ out)
{
  int tid = blockIdx.x*256 + threadIdx.x;
  int c = tid >> 10;
  int j = tid & (NBF32-1);
  const float2* src = in + (size_t)c * STR;
  float2 v[32];
  #pragma unroll
  for (int r = 0; r < 32; ++r) v[r] = src[j + (r << 10)];
  constexpr int NS = 1 << LG;
  int jm = j & (NS - 1);
  if constexpr (LG > 0) {
    float ang = (float)S * (2.0f*PI_F) * (float)jm / (float)(NS*32);
    stage_twiddle32<S>(v, ang);
  }
  dft32<S>(v);
  int idxD = ((j >> LG) << (LG+5)) + jm;
  float2* dst = out + (size_t)c * STR + idxD;
  #pragma unroll
  for (int r = 0; r < 32; ++r) dst[(size_t)(r << LG)] = v[r];
}

// ---------- whitening: rfft unpack + running-abs-mean + tapers, in place ----------
__device__ __forceinline__ int padidx(int m){ return m + (m >> 5); }

__global__ __launch_bounds__(1024) void whiten_kernel(float2* __restrict__ buf)
{
  const int ch = blockIdx.x;
  const int t  = threadIdx.x;
  float2* Z = buf + (size_t)ch * STR;
  __shared__ float s[33793];     // 32769 magnitudes, padded every 32
  __shared__ float wsums[16];

  float2 X[33];
  // phase 1: unpack X[k] from Z[k], Z[N-k]; magnitudes to LDS
  #pragma unroll
  for (int i = 0; i < 33; ++i) {
    int k = i*1024 + t;
    if (i < 32 || t == 0) {
      float2 zk = Z[k & (NFFT-1)];
      float2 zn = Z[(NFFT - k) & (NFFT-1)];
      float2 xe = make_float2(0.5f*(zk.x+zn.x), 0.5f*(zk.y-zn.y));
      float2 xh = make_float2(0.5f*(zk.x-zn.x), 0.5f*(zk.y+zn.y)); // (zk-conj(zn))/2
      float2 xo = make_float2(xh.y, -xh.x);                        // /i
      float ang = -PI_F * (float)k * (1.0f/32768.0f);
      float sn, cs; __sincosf(ang, &sn, &cs);
      float2 w = make_float2(cs, sn);
      X[i] = cadd(xe, cmul(w, xo));
      s[padidx(k)] = sqrtf(X[i].x*X[i].x + X[i].y*X[i].y);
    }
  }
  __syncthreads();

  // phase 2: block-wide inclusive cumsum of magnitudes (in place in LDS)
  const int base = t*32;
  float sum = 0.f;
  #pragma unroll
  for (int q = 0; q < 32; ++q) sum += s[padidx(base+q)];
  if (t == 1023) sum += s[padidx(32768)];
  const int lane = t & 63, wid = t >> 6;
  float v = sum;
  #pragma unroll
  for (int off = 1; off < 64; off <<= 1) {
    float u = __shfl_up(v, off);
    if (lane >= off) v += u;
  }
  if (lane == 63) wsums[wid] = v;
  __syncthreads();
  float wexcl = 0.f;
  for (int w = 0; w < 16; ++w) wexcl += (w < wid) ? wsums[w] : 0.f;
  float run = wexcl + (v - sum);       // exclusive prefix of this thread's chunk
  #pragma unroll
  for (int q = 0; q < 32; ++q) {
    int idx = padidx(base+q);
    run += s[idx];
    s[idx] = run;
  }
  if (t == 1023) { int idx = padidx(32768); run += s[idx]; s[idx] = run; }
  __syncthreads();

  // phase 3: smoothed = edge-clamped 655-bin box mean; whiten + taper; write W in place
  const float a0 = s[padidx(0)];
  const float alast = s[padidx(32768)] - s[padidx(32767)];
  #pragma unroll
  for (int i = 0; i < 33; ++i) {
    int k = i*1024 + t;
    if (i < 32 || t == 0) {
      int hi = k + 327; if (hi > 32768) hi = 32768;
      int lom1 = k - 328;
      float Shi = s[padidx(hi)];
      float Slo = (lom1 >= 0) ? s[padidx(lom1)] : 0.f;
      float lc = (k < 327) ? (float)(327 - k) : 0.f;
      float rc = (k > 32441) ? (float)(k - 32441) : 0.f;
      float smoothed = (lc*a0 + (Shi - Slo) + rc*alast) * (1.0f/655.0f);
      float2 wv;
      if (smoothed > 0.f) {
        float inv = 1.0f / smoothed;
        wv = make_float2(X[i].x*inv, X[i].y*inv);
      } else wv = make_float2(0.f, 0.f);
      float tp = 1.0f;
      if (k < 131)        { float th = (float)k * (PI_F/260.0f);           float sn = __sinf(th); tp = sn*sn; }
      else if (k >= 13108){ float th = (float)(k-13108) * (PI_F/39320.0f); float cs = __cosf(th); tp = cs*cs; }
      wv.x *= tp; wv.y *= tp;
      Z[k] = wv;
    }
  }
}

// ---------- cross-spectrum + irfft packing: Zinv = (Xe + i*Xo)/N ----------
__global__ __launch_bounds__(256) void cross_pack(const float2* __restrict__ W, float2* __restrict__ Zo, int cb)
{
  int tid = blockIdx.x*256 + threadIdx.x;
  int c = tid / 16640;
  int k = tid - c*16640;
  if (k > 16384 || c >= cb) return;
  const float2* W1 = W + (size_t)c * STR;
  const float2* W2 = W + (size_t)(cb + c) * STR;
  float2 a1 = W1[k],        b1 = W2[k];
  float2 a2 = W1[NFFT - k], b2 = W2[NFFT - k];
  // C = conj(W1)*W2
  float2 Ck = make_float2(a1.x*b1.x + a1.y*b1.y, a1.x*b1.y - a1.y*b1.x);
  float2 Cn = make_float2(a2.x*b2.x + a2.y*b2.y, a2.x*b2.y - a2.y*b2.x);
  float ang = PI_F * (float)k * (1.0f/32768.0f);
  float sn, cs; __sincosf(ang, &sn, &cs);
  const float scale = 1.0f/32768.0f;
  float2* dst = Zo + (size_t)c * STR;
  // Zinv[k]: Xe=(Ck+conj(Cn))/2, Xo=e^{+iπk/N}(Ck-conj(Cn))/2
  {
    float2 xe = make_float2(0.5f*(Ck.x+Cn.x), 0.5f*(Ck.y-Cn.y));
    float2 d  = make_float2(0.5f*(Ck.x-Cn.x), 0.5f*(Ck.y+Cn.y));
    float2 w  = make_float2(cs, sn);
    float2 xo = cmul(w, d);
    dst[k] = make_float2((xe.x - xo.y)*scale, (xe.y + xo.x)*scale);
  }
  if (k > 0 && k < 16384) {
    // Zinv[N-k]: e^{iπ(N-k)/N} = (-cs, sn)
    float2 xe = make_float2(0.5f*(Cn.x+Ck.x), 0.5f*(Cn.y-Ck.y));
    float2 d  = make_float2(0.5f*(Cn.x-Ck.x), 0.5f*(Cn.y+Ck.y));
    float2 w  = make_float2(-cs, sn);
    float2 xo = cmul(w, d);
    dst[NFFT - k] = make_float2((xe.x - xo.y)*scale, (xe.y + xo.x)*scale);
  }
}

// ---------- inverse final pass (Ns=1024, radix-32), fused unpack + roll + slice ----------
__global__ __launch_bounds__(256) void fft_inv_final32(const float2* __restrict__ in, float* __restrict__ out, int ch0)
{
  int tid = blockIdx.x*256 + threadIdx.x;
  int c = tid >> 10;
  int j = tid & (NBF32-1);
  const float2* src = in + (size_t)c * STR;
  float2 v[32];
  #pragma unroll
  for (int r = 0; r < 32; ++r) v[r] = src[j + (r << 10)];
  float ang = (2.0f*PI_F) * (float)j * (1.0f/32768.0f);
  stage_twiddle32<1>(v, ang);
  dft32<1>(v);
  float* o = out + (size_t)(ch0 + c) * XCOR;
  // cc[m]: m=2n -> Re, m=2n+1 -> Im ; out[j]=cc[(j-29999) mod 65536]
  #pragma unroll
  for (int r = 0; r < 32; ++r) {
    int n = j + (r << 10);
    int m = 2*n;
    int j1 = (m <= 29999) ? (m + 29999) : ((m >= 35537) ? (m - 35537) : -1);
    if (j1 >= 0) o[j1] = v[r].x;
    int m2 = m + 1;
    int j2 = (m2 <= 29999) ? (m2 + 29999) : ((m2 >= 35537) ? (m2 - 35537) : -1);
    if (j2 >= 0) o[j2] = v[r].y;
  }
}

__global__ void diag_kernel(float* out, float vv){ if (threadIdx.x==0 && blockIdx.x==0) out[0] = vv; }

extern "C" void kernel_launch(void* const* d_in, const int* in_sizes, int n_in,
                              void* d_out, int out_size, void* d_ws, size_t ws_size,
                              hipStream_t stream)
{
  const float* d1 = (const float*)d_in[0];
  const float* d2 = (const float*)d_in[1];
  float* out = (float*)d_out;

  // bytes per channel-pair of batch: 2 buffers * 2 arrays * STR complex
  const size_t bytesPerCh = 2ULL * 2ULL * (size_t)STR * sizeof(float2); // 1,048,640
  int CB = (int)(ws_size / bytesPerCh);
  if (CB > NCH) CB = NCH;
  if (CB < 1) { diag_kernel<<<1,1,0,stream>>>(out, (float)ws_size); return; }

  float2* bufA = (float2*)d_ws;
  float2* bufB = bufA + (size_t)2 * CB * STR;

  for (int ch0 = 0; ch0 < NCH; ch0 += CB) {
    int cb = (NCH - ch0 < CB) ? (NCH - ch0) : CB;
    int nch2 = 2*cb;
    dim3 thr(256);
    dim3 blkF(nch2*4), blkI(cb*4);

    // forward FFT (both arrays batched), 3 radix-32 Stockham passes
    fft_fwd_p1_r32    <<<blkF, thr, 0, stream>>>(d1, d2, bufA, cb, ch0);
    fft_pass32<5,-1>  <<<blkF, thr, 0, stream>>>(bufA, bufB);
    fft_pass32<10,-1> <<<blkF, thr, 0, stream>>>(bufB, bufA);

    // spectral whitening in place (unpack -> running abs mean -> taper)
    whiten_kernel     <<<dim3(nch2), dim3(1024), 0, stream>>>(bufA);

    // conj(W1)*W2 + irfft pack (scale 1/N folded in)
    cross_pack        <<<dim3(cb*65), thr, 0, stream>>>(bufA, bufB, cb);

    // inverse FFT, 3 radix-32 passes; final fused with roll + central slice
    fft_pass32<0,1>   <<<blkI, thr, 0, stream>>>(bufB, bufA);
    fft_pass32<5,1>   <<<blkI, thr, 0, stream>>>(bufA, bufB);
    fft_inv_final32   <<<blkI, thr, 0, stream>>>(bufB, out, ch0);
  }
}